// Round 1
// baseline (534.497 us; speedup 1.0000x reference)
//
#include <hip/hip_runtime.h>

#define DEV __device__ __forceinline__

typedef __attribute__((ext_vector_type(4))) float floatx4;
typedef __attribute__((ext_vector_type(8))) short short8;

DEV unsigned short f2bf(float f) {
  unsigned u = __float_as_uint(f);
  u += 0x7FFF + ((u >> 16) & 1);
  return (unsigned short)(u >> 16);
}
DEV float bf2f(unsigned short h) { return __uint_as_float(((unsigned)h) << 16); }

#define GLD16(g, l)                                                            \
  __builtin_amdgcn_global_load_lds(                                            \
      (const __attribute__((address_space(1))) void*)(g),                      \
      (__attribute__((address_space(3))) void*)(l), 16, 0, 0)

// ---------------------------------------------------------------- weights
// W [K=1024, N=1024] fp32 -> Wt [N,K] bf16 (so GEMM B-operand is k-contiguous)
__global__ void k_wt(const float* __restrict__ w0, const float* __restrict__ w1,
                     const float* __restrict__ w2, const float* __restrict__ w3,
                     unsigned short* __restrict__ wt) {
  __shared__ float t[64][65];
  const float* wsel = (blockIdx.z == 0) ? w0
                    : (blockIdx.z == 1) ? w1
                    : (blockIdx.z == 2) ? w2 : w3;
  unsigned short* out = wt + (size_t)blockIdx.z * 1024 * 1024;
  const int tx = threadIdx.x, ty = threadIdx.y;
  const int k0 = blockIdx.x * 64, n0 = blockIdx.y * 64;
  for (int i = ty; i < 64; i += 4)
    t[i][tx] = wsel[(size_t)(k0 + i) * 1024 + n0 + tx];
  __syncthreads();
  for (int i = ty; i < 64; i += 4)
    out[(size_t)(n0 + i) * 1024 + k0 + tx] = f2bf(t[tx][i]);
}

// ---------------------------------------------------------------- x + pe
__global__ void k_addpe(const float* __restrict__ x, const float* __restrict__ pe,
                        float* __restrict__ xf, unsigned short* __restrict__ xb) {
  const int idx = blockIdx.x * 256 + threadIdx.x;  // float4 index, 2M total
  const int row = idx >> 8;                        // token 0..8191
  const int c4 = idx & 255;
  const int s = row & 2047;
  const float4 xv = ((const float4*)x)[idx];
  const float4 pv = ((const float4*)pe)[s * 256 + c4];
  float4 r;
  r.x = xv.x + pv.x; r.y = xv.y + pv.y; r.z = xv.z + pv.z; r.w = xv.w + pv.w;
  ((float4*)xf)[idx] = r;
  ushort4 o;
  o.x = f2bf(r.x); o.y = f2bf(r.y); o.z = f2bf(r.z); o.w = f2bf(r.w);
  ((ushort4*)xb)[idx] = o;
}

// ---------------------------------------------------------------- GEMM
// C[M,1024] = A[M,1024] * Bt[1024(N),1024(K)]^T + bias
// MODE 0: out[b,h,s,d] bf16   MODE 2: out[b,h,d,s] bf16   MODE 3: out[row,col] bf16
template <int MODE>
__global__ __launch_bounds__(256) void k_gemm(
    const unsigned short* __restrict__ A, const unsigned short* __restrict__ Bt,
    const float* __restrict__ bias, unsigned short* __restrict__ out) {
  __shared__ unsigned short As[128 * 32];
  __shared__ unsigned short Bs[128 * 32];
  const int tid = threadIdx.x;
  const int lane = tid & 63, wave = tid >> 6;
  const int quad = lane >> 4, l16 = lane & 15;
  const int wm = wave >> 1, wn = wave & 1;
  const int rb = blockIdx.x * 128, cb = blockIdx.y * 128;

  floatx4 acc[4][4];
  const floatx4 vzero = {0.f, 0.f, 0.f, 0.f};
#pragma unroll
  for (int i = 0; i < 4; ++i)
#pragma unroll
    for (int j = 0; j < 4; ++j) acc[i][j] = vzero;

  for (int k0 = 0; k0 < 1024; k0 += 32) {
#pragma unroll
    for (int r = 0; r < 2; ++r) {
      const int c = r * 256 + tid;
      const int arow = c >> 2, koff = (c & 3) << 3;
      GLD16(A + (size_t)(rb + arow) * 1024 + k0 + koff,
            As + (size_t)(r * 256 + wave * 64) * 8);
      GLD16(Bt + (size_t)(cb + arow) * 1024 + k0 + koff,
            Bs + (size_t)(r * 256 + wave * 64) * 8);
    }
    __syncthreads();
    short8 fa[4], fb[4];
#pragma unroll
    for (int i = 0; i < 4; ++i) {
      fa[i] = *(const short8*)(As + (wm * 64 + i * 16 + l16) * 32 + quad * 8);
      fb[i] = *(const short8*)(Bs + (wn * 64 + i * 16 + l16) * 32 + quad * 8);
    }
#pragma unroll
    for (int mi = 0; mi < 4; ++mi)
#pragma unroll
      for (int ni = 0; ni < 4; ++ni)
        acc[mi][ni] =
            __builtin_amdgcn_mfma_f32_16x16x32_bf16(fa[mi], fb[ni], acc[mi][ni], 0, 0, 0);
    __syncthreads();
  }

#pragma unroll
  for (int ni = 0; ni < 4; ++ni) {
    const int col = cb + wn * 64 + ni * 16 + l16;
    const float bv = bias[col];
#pragma unroll
    for (int mi = 0; mi < 4; ++mi) {
#pragma unroll
      for (int r = 0; r < 4; ++r) {
        const int row = rb + wm * 64 + mi * 16 + quad * 4 + r;
        const float val = acc[mi][ni][r] + bv;
        if (MODE == 0) {
          const int b = row >> 11, s = row & 2047, h = col >> 6, d = col & 63;
          out[((size_t)(b * 16 + h) * 2048 + s) * 64 + d] = f2bf(val);
        } else if (MODE == 2) {
          const int b = row >> 11, s = row & 2047, h = col >> 6, d = col & 63;
          out[((size_t)(b * 16 + h) * 64 + d) * 2048 + s] = f2bf(val);
        } else {
          out[(size_t)row * 1024 + col] = f2bf(val);
        }
      }
    }
  }
}

// ---------------------------------------------------------------- flash attn
// Q,K: [b*h, 2048, 64] bf16; Vt: [b*h, 64, 2048] bf16; AO: [b*2048, 1024] bf16
__global__ __launch_bounds__(256) void k_flash(
    const unsigned short* __restrict__ Q, const unsigned short* __restrict__ Kb,
    const unsigned short* __restrict__ Vt, unsigned short* __restrict__ AO) {
  __shared__ unsigned short Ks[64 * 64];
  __shared__ unsigned short Vs[64 * 64];
  __shared__ unsigned short Ps[4][16 * 64];
  const int tid = threadIdx.x, lane = tid & 63, wave = tid >> 6;
  const int quad = lane >> 4, l16 = lane & 15;
  const int qt = blockIdx.x, bh = blockIdx.y;
  const int b = bh >> 4, h = bh & 15;

  const unsigned short* Qb = Q + ((size_t)bh * 2048 + qt * 64 + wave * 16) * 64;
  short8 aq[2];
#pragma unroll
  for (int c = 0; c < 2; ++c)
    aq[c] = *(const short8*)(Qb + (size_t)l16 * 64 + c * 32 + quad * 8);

  const floatx4 vzero = {0.f, 0.f, 0.f, 0.f};
  floatx4 o[4];
#pragma unroll
  for (int di = 0; di < 4; ++di) o[di] = vzero;
  float m_i[4] = {-1e30f, -1e30f, -1e30f, -1e30f};
  float l_i[4] = {0.f, 0.f, 0.f, 0.f};

  const unsigned short* Kh = Kb + (size_t)bh * 2048 * 64;
  const unsigned short* Vh = Vt + (size_t)bh * 64 * 2048;

  for (int kt = 0; kt < 32; ++kt) {
#pragma unroll
    for (int r = 0; r < 2; ++r) {
      const int c = r * 256 + tid;
      const int rw = c >> 3, off = (c & 7) << 3;
      GLD16(Kh + (size_t)(kt * 64 + rw) * 64 + off,
            Ks + (size_t)(r * 256 + wave * 64) * 8);
      GLD16(Vh + (size_t)rw * 2048 + kt * 64 + off,
            Vs + (size_t)(r * 256 + wave * 64) * 8);
    }
    __syncthreads();

    floatx4 sc[4];
#pragma unroll
    for (int ni = 0; ni < 4; ++ni) {
      floatx4 t = vzero;
#pragma unroll
      for (int c = 0; c < 2; ++c) {
        const short8 bk =
            *(const short8*)(Ks + (ni * 16 + l16) * 64 + c * 32 + quad * 8);
        t = __builtin_amdgcn_mfma_f32_16x16x32_bf16(aq[c], bk, t, 0, 0, 0);
      }
      sc[ni] = t * 0.125f;  // 1/sqrt(64)
    }

    float al[4];
#pragma unroll
    for (int r = 0; r < 4; ++r) {
      float m = fmaxf(fmaxf(sc[0][r], sc[1][r]), fmaxf(sc[2][r], sc[3][r]));
#pragma unroll
      for (int msk = 1; msk < 16; msk <<= 1) m = fmaxf(m, __shfl_xor(m, msk));
      const float mn = fmaxf(m_i[r], m);
      float sum = 0.f;
#pragma unroll
      for (int ni = 0; ni < 4; ++ni) {
        const float p = __expf(sc[ni][r] - mn);
        sc[ni][r] = p;
        sum += p;
      }
#pragma unroll
      for (int msk = 1; msk < 16; msk <<= 1) sum += __shfl_xor(sum, msk);
      al[r] = __expf(m_i[r] - mn);
      l_i[r] = l_i[r] * al[r] + sum;
      m_i[r] = mn;
    }
#pragma unroll
    for (int di = 0; di < 4; ++di)
#pragma unroll
      for (int r = 0; r < 4; ++r) o[di][r] *= al[r];

    // P: C-layout (row=quad*4+r, col=ni*16+l16) -> LDS -> A-layout
    unsigned short* Pw = Ps[wave];
#pragma unroll
    for (int ni = 0; ni < 4; ++ni)
#pragma unroll
      for (int r = 0; r < 4; ++r)
        Pw[(quad * 4 + r) * 64 + ni * 16 + l16] = f2bf(sc[ni][r]);
    __syncthreads();

#pragma unroll
    for (int c = 0; c < 2; ++c) {
      const short8 ap = *(const short8*)(Pw + (size_t)l16 * 64 + c * 32 + quad * 8);
#pragma unroll
      for (int di = 0; di < 4; ++di) {
        const short8 bv =
            *(const short8*)(Vs + (di * 16 + l16) * 64 + c * 32 + quad * 8);
        o[di] = __builtin_amdgcn_mfma_f32_16x16x32_bf16(ap, bv, o[di], 0, 0, 0);
      }
    }
    __syncthreads();
  }

#pragma unroll
  for (int di = 0; di < 4; ++di) {
#pragma unroll
    for (int r = 0; r < 4; ++r) {
      const float val = o[di][r] / l_i[r];
      const int s = qt * 64 + wave * 16 + quad * 4 + r;
      const int col = h * 64 + di * 16 + l16;
      AO[((size_t)b * 2048 + s) * 1024 + col] = f2bf(val);
    }
  }
}

// ---------------------------------------------------------------- residual+LN
__global__ __launch_bounds__(256) void k_ln(
    const unsigned short* __restrict__ proj, const float* __restrict__ xpe,
    const float* __restrict__ gamma, const float* __restrict__ beta,
    float* __restrict__ out) {
  const int row = blockIdx.x, tid = threadIdx.x;
  const int lane = tid & 63, wave = tid >> 6;
  const float4 xv = ((const float4*)(xpe + (size_t)row * 1024))[tid];
  const ushort4 pv = ((const ushort4*)(proj + (size_t)row * 1024))[tid];
  const float h0 = xv.x + bf2f(pv.x);
  const float h1 = xv.y + bf2f(pv.y);
  const float h2 = xv.z + bf2f(pv.z);
  const float h3 = xv.w + bf2f(pv.w);
  float s = h0 + h1 + h2 + h3;
  float s2 = h0 * h0 + h1 * h1 + h2 * h2 + h3 * h3;
#pragma unroll
  for (int m = 1; m < 64; m <<= 1) {
    s += __shfl_xor(s, m);
    s2 += __shfl_xor(s2, m);
  }
  __shared__ float rs[4], rq[4];
  if (lane == 0) { rs[wave] = s; rq[wave] = s2; }
  __syncthreads();
  s = rs[0] + rs[1] + rs[2] + rs[3];
  s2 = rq[0] + rq[1] + rq[2] + rq[3];
  const float mu = s * (1.f / 1024.f);
  const float var = s2 * (1.f / 1024.f) - mu * mu;
  const float rstd = rsqrtf(var + 1e-5f);
  const float4 gv = ((const float4*)gamma)[tid];
  const float4 bv = ((const float4*)beta)[tid];
  float4 ov;
  ov.x = (h0 - mu) * rstd * gv.x + bv.x;
  ov.y = (h1 - mu) * rstd * gv.y + bv.y;
  ov.z = (h2 - mu) * rstd * gv.z + bv.z;
  ov.w = (h3 - mu) * rstd * gv.w + bv.w;
  ((float4*)(out + (size_t)row * 1024))[tid] = ov;
}

// ---------------------------------------------------------------- launch
extern "C" void kernel_launch(void* const* d_in, const int* in_sizes, int n_in,
                              void* d_out, int out_size, void* d_ws, size_t ws_size,
                              hipStream_t stream) {
  const float* x = (const float*)d_in[0];
  const float* wq = (const float*)d_in[1];
  const float* bq = (const float*)d_in[2];
  const float* wk = (const float*)d_in[3];
  const float* bk = (const float*)d_in[4];
  const float* wv = (const float*)d_in[5];
  const float* bv = (const float*)d_in[6];
  const float* wo = (const float*)d_in[7];
  const float* bo = (const float*)d_in[8];
  const float* gamma = (const float*)d_in[9];
  const float* beta = (const float*)d_in[10];
  const float* pe = (const float*)d_in[11];

  if (ws_size < 125829120) return;  // need 120 MB scratch

  char* w = (char*)d_ws;
  unsigned short* wt = (unsigned short*)(w);               // 4x 1024x1024 bf16 (8 MB)
  float* xpef = (float*)(w + 8388608);                     // 8192x1024 f32 (32 MB)
  unsigned short* xpeb = (unsigned short*)(w + 41943040);  // 8192x1024 bf16 (16 MB)
  unsigned short* qb = (unsigned short*)(w + 58720256);    // 16 MB
  unsigned short* kb = (unsigned short*)(w + 75497472);    // 16 MB
  unsigned short* vtb = (unsigned short*)(w + 92274688);   // 16 MB
  unsigned short* aob = (unsigned short*)(w + 109051904);  // 16 MB
  unsigned short* projb = qb;                              // alias: Q dead after flash

  k_wt<<<dim3(16, 16, 4), dim3(64, 4), 0, stream>>>(wq, wk, wv, wo, wt);
  k_addpe<<<8192, 256, 0, stream>>>(x, pe, xpef, xpeb);
  k_gemm<0><<<dim3(64, 8), 256, 0, stream>>>(xpeb, wt, bq, qb);
  k_gemm<0><<<dim3(64, 8), 256, 0, stream>>>(xpeb, wt + 1048576, bk, kb);
  k_gemm<2><<<dim3(64, 8), 256, 0, stream>>>(xpeb, wt + 2097152, bv, vtb);
  k_flash<<<dim3(32, 64), 256, 0, stream>>>(qb, kb, vtb, aob);
  k_gemm<3><<<dim3(64, 8), 256, 0, stream>>>(aob, wt + 3145728, bo, projb);
  k_ln<<<8192, 256, 0, stream>>>(projb, xpef, gamma, beta, (float*)d_out);
}